// Round 8
// baseline (42.120 us; speedup 1.0000x reference)
//
#include <hip/hip_runtime.h>
#include <hip/hip_bf16.h>

#define D 4096
#define NP 8

typedef short bf16x8 __attribute__((ext_vector_type(8)));
typedef float f32x4 __attribute__((ext_vector_type(4)));
typedef unsigned short u16x8 __attribute__((ext_vector_type(8)));

__device__ __forceinline__ ushort f2bf(float f) {
    __hip_bfloat16 h = __float2bfloat16(f);
    return __builtin_bit_cast(ushort, h);
}

// ---------------------------------------------------------------------------
// Pre-kernel (validated since R3): all A-matrices in MFMA fragment order.
// Image g at Af + g*4096: g in [0,64) = A1(bk=g); g in [64,128) = A0(bj=g-64).
//   frag fi = strip*2+mk, lane, e:
//     coef = strip*16 + (lane&15), match = mk*32 + (lane>>4)*8 + e
//   A1: M[k'][l] = sum_p c1[p,k'] * (perm1[p,k']==l)
//   A0: M[j][i]  = sum_p c0[p,j]  * (perm0[p,j]==i)
// ---------------------------------------------------------------------------
__global__ __launch_bounds__(256) void psw_pre(
    const float* __restrict__ c0, const float* __restrict__ c1,
    const int* __restrict__ p0, const int* __restrict__ p1,
    ushort* __restrict__ Af)
{
    const int B = blockIdx.x;
    const int t = threadIdx.x;
    const bool isA0 = (B >= 64);
    const int blk = B & 63;
    const int* qa = isA0 ? p0 : p1;
    const float* ca = isA0 ? c0 : c1;
    const int fi = t >> 5;
    const int strip = fi >> 1, mk = fi & 1;

    u16x8 res[2];
    #pragma unroll
    for (int sub = 0; sub < 2; ++sub) {
        const int L = (2 * t + sub) & 63;
        const int coef = blk * 64 + strip * 16 + (L & 15);
        const int kbase = mk * 32 + (L >> 4) * 8;
        int q[NP]; float c[NP];
        #pragma unroll
        for (int p = 0; p < NP; ++p) {
            q[p] = qa[p * D + coef] - blk * 64;
            c[p] = ca[p * D + coef];
        }
        #pragma unroll
        for (int e = 0; e < 8; ++e) {
            const int match = kbase + e;
            float v = 0.f;
            #pragma unroll
            for (int p = 0; p < NP; ++p) v += (q[p] == match) ? c[p] : 0.f;
            res[sub][e] = f2bf(v);
        }
    }
    *reinterpret_cast<u16x8*>(&Af[B * 4096 + t * 16])     = res[0];
    *reinterpret_cast<u16x8*>(&Af[B * 4096 + t * 16 + 8]) = res[1];
}

// ---------------------------------------------------------------------------
// Main: 4 independent waves per block, ONE 64x64 TILE PER WAVE, no barriers,
// wave-private LDS. All 24 VMEM loads issued up front and PINNED with a
// compiler memory clobber (un-sinkable), then mask -> mm1 -> LDS transpose
// -> mm2 -> dwordx4 stores. Latency hiding = 24 loads in flight x 16 waves/CU.
// ---------------------------------------------------------------------------
__global__ __launch_bounds__(256, 4) void psw_main(
    const float* __restrict__ X,
    const ushort* __restrict__ Af,
    float* __restrict__ out)
{
    __shared__ ushort T1t[4][1024];  // per-wave strip^T [kk 16][i 64] bf16 swz

    const int t    = threadIdx.x;
    const int lane = t & 63;
    const int w    = t >> 6;
    const int m  = lane & 15;
    const int lq = lane >> 4;
    const int bj = blockIdx.x >> 4;              // 64 row blocks
    const int bk = (blockIdx.x & 15) * 4 + w;    // wave's column block

    // ---- issue ALL global loads (16 X dwordx4 + 8 A0 dwordx4) --------------
    f32x4 xl[8][2];                // f = it*2+mk: row it*16+m, l = mk*32+lq*8..
    #pragma unroll
    for (int f = 0; f < 8; ++f) {
        const int it = f >> 1, mk = f & 1;
        const float* p = &X[(size_t)(bj * 64 + it * 16 + m) * D
                            + bk * 64 + mk * 32 + lq * 8];
        xl[f][0] = *reinterpret_cast<const f32x4*>(p);
        xl[f][1] = *reinterpret_cast<const f32x4*>(p + 4);
    }
    bf16x8 a0fr[8];                // A0(bj) image, reused by all 4 nt-strips
    #pragma unroll
    for (int f = 0; f < 8; ++f)
        a0fr[f] = *reinterpret_cast<const bf16x8*>(
            &Af[(size_t)(64 + bj) * 4096 + (f * 64 + lane) * 8]);

    // pin: loads may not sink past this point (memory clobber), and the
    // scheduler may not interleave the VALU phase above it.
    asm volatile("" ::: "memory");
    __builtin_amdgcn_sched_barrier(0);

    // ---- mask top-2-of-4 (lane-local aligned groups), cvt to bf16 ----------
    bf16x8 wfr[8];
    #pragma unroll
    for (int f = 0; f < 8; ++f) {
        #pragma unroll
        for (int h = 0; h < 2; ++h) {
            const f32x4 g = xl[f][h];
            const float a0v = fabsf(g[0]), a1v = fabsf(g[1]),
                        a2v = fabsf(g[2]), a3v = fabsf(g[3]);
            const int b01 = a1v >= a0v, b02 = a2v >= a0v, b03 = a3v >= a0v;
            const int b12 = a2v >= a1v, b13 = a3v >= a1v, b23 = a3v >= a2v;
            const int c0n = b01 + b02 + b03;
            const int c1n = (1 - b01) + b12 + b13;
            const int c2n = (2 - b02 - b12) + b23;
            const int c3n = 3 - b03 - b13 - b23;
            wfr[f][h * 4 + 0] = (short)f2bf(c0n < 2 ? g[0] : 0.f);
            wfr[f][h * 4 + 1] = (short)f2bf(c1n < 2 ? g[1] : 0.f);
            wfr[f][h * 4 + 2] = (short)f2bf(c2n < 2 ? g[2] : 0.f);
            wfr[f][h * 4 + 3] = (short)f2bf(c3n < 2 ? g[3] : 0.f);
        }
    }

    // ---- per 16-col output strip: mm1 -> LDS transpose -> mm2 -> store -----
    #pragma unroll
    for (int nt = 0; nt < 4; ++nt) {
        // A1 strip frags (L2/L3-hot)
        bf16x8 a1fr[2];
        #pragma unroll
        for (int mk = 0; mk < 2; ++mk)
            a1fr[mk] = *reinterpret_cast<const bf16x8*>(
                &Af[(size_t)bk * 4096 + ((nt * 2 + mk) * 64 + lane) * 8]);

        // mm1: T1[:, nt*16+0..15] = mask(X) x A1strip
        f32x4 acc1[4];
        #pragma unroll
        for (int it = 0; it < 4; ++it) acc1[it] = (f32x4){0.f, 0.f, 0.f, 0.f};
        #pragma unroll
        for (int mk = 0; mk < 2; ++mk)
            #pragma unroll
            for (int it = 0; it < 4; ++it)
                acc1[it] = __builtin_amdgcn_mfma_f32_16x16x32_bf16(
                    wfr[it * 2 + mk], a1fr[mk], acc1[it], 0, 0, 0);

        // T1 strip^T to wave-private LDS (in-order within wave, no barrier)
        #pragma unroll
        for (int it = 0; it < 4; ++it) {
            ushort4 tv;
            tv.x = f2bf(acc1[it][0]); tv.y = f2bf(acc1[it][1]);
            tv.z = f2bf(acc1[it][2]); tv.w = f2bf(acc1[it][3]);
            *reinterpret_cast<ushort4*>(
                reinterpret_cast<char*>(T1t[w]) + m * 128
                + ((it * 32 + lq * 8) ^ ((m & 7) << 4))) = tv;
        }

        // mm2: out^T[kk strip][j] = T1strip^T (A) x A0 (B)
        f32x4 accD[4];
        #pragma unroll
        for (int jt = 0; jt < 4; ++jt) accD[jt] = (f32x4){0.f, 0.f, 0.f, 0.f};
        #pragma unroll
        for (int ik = 0; ik < 2; ++ik) {
            const bf16x8 t1fr = *reinterpret_cast<const bf16x8*>(
                reinterpret_cast<char*>(T1t[w]) + m * 128
                + ((ik * 64 + lq * 16) ^ ((m & 7) << 4)));
            #pragma unroll
            for (int jt = 0; jt < 4; ++jt)
                accD[jt] = __builtin_amdgcn_mfma_f32_16x16x32_bf16(
                    t1fr, a0fr[jt * 2 + ik], accD[jt], 0, 0, 0);
        }

        // stores: lane holds out[j=jt*16+m][kk = nt*16 + lq*4 .. +3]
        #pragma unroll
        for (int jt = 0; jt < 4; ++jt)
            *reinterpret_cast<f32x4*>(
                &out[(size_t)(bj * 64 + jt * 16 + m) * D
                     + bk * 64 + nt * 16 + lq * 4]) = accD[jt];
    }
}

extern "C" void kernel_launch(void* const* d_in, const int* in_sizes, int n_in,
                              void* d_out, int out_size, void* d_ws, size_t ws_size,
                              hipStream_t stream) {
    const float* X     = (const float*)d_in[0];
    const float* c0    = (const float*)d_in[1];
    const float* c1    = (const float*)d_in[2];
    // d_in[3] = mask (bool) -- recomputed in-kernel from X, not read
    const int*   perm0 = (const int*)d_in[4];
    const int*   perm1 = (const int*)d_in[5];
    float* out = (float*)d_out;
    ushort* Af = (ushort*)d_ws;    // 128 * 4096 ushorts = 1 MiB

    psw_pre<<<dim3(128), 256, 0, stream>>>(c0, c1, perm0, perm1, Af);
    psw_main<<<dim3(1024), 256, 0, stream>>>(X, Af, out);
}

// Round 9
// 35.549 us; speedup vs baseline: 1.1848x; 1.1848x over previous
//
#include <hip/hip_runtime.h>
#include <hip/hip_bf16.h>

#define D 4096
#define NP 8

typedef short bf16x8 __attribute__((ext_vector_type(8)));
typedef float f32x4 __attribute__((ext_vector_type(4)));
typedef unsigned short u16x8 __attribute__((ext_vector_type(8)));

__device__ __forceinline__ ushort f2bf(float f) {
    __hip_bfloat16 h = __float2bfloat16(f);
    return __builtin_bit_cast(ushort, h);
}

// ---------------------------------------------------------------------------
// Pre-kernel (validated since R3): all A-matrices in MFMA fragment order.
// Image g at Af + g*4096: g in [0,64) = A1(bk=g); g in [64,128) = A0(bj=g-64).
//   frag fi = strip*2+mk, lane, e:
//     coef = strip*16 + (lane&15), match = mk*32 + (lane>>4)*8 + e
//   A1: M[k'][l] = sum_p c1[p,k'] * (perm1[p,k']==l)
//   A0: M[j][i]  = sum_p c0[p,j]  * (perm0[p,j]==i)
// ---------------------------------------------------------------------------
__global__ __launch_bounds__(256) void psw_pre(
    const float* __restrict__ c0, const float* __restrict__ c1,
    const int* __restrict__ p0, const int* __restrict__ p1,
    ushort* __restrict__ Af)
{
    const int B = blockIdx.x;
    const int t = threadIdx.x;
    const bool isA0 = (B >= 64);
    const int blk = B & 63;
    const int* qa = isA0 ? p0 : p1;
    const float* ca = isA0 ? c0 : c1;
    const int fi = t >> 5;
    const int strip = fi >> 1, mk = fi & 1;

    u16x8 res[2];
    #pragma unroll
    for (int sub = 0; sub < 2; ++sub) {
        const int L = (2 * t + sub) & 63;
        const int coef = blk * 64 + strip * 16 + (L & 15);
        const int kbase = mk * 32 + (L >> 4) * 8;
        int q[NP]; float c[NP];
        #pragma unroll
        for (int p = 0; p < NP; ++p) {
            q[p] = qa[p * D + coef] - blk * 64;
            c[p] = ca[p * D + coef];
        }
        #pragma unroll
        for (int e = 0; e < 8; ++e) {
            const int match = kbase + e;
            float v = 0.f;
            #pragma unroll
            for (int p = 0; p < NP; ++p) v += (q[p] == match) ? c[p] : 0.f;
            res[sub][e] = f2bf(v);
        }
    }
    *reinterpret_cast<u16x8*>(&Af[B * 4096 + t * 16])     = res[0];
    *reinterpret_cast<u16x8*>(&Af[B * 4096 + t * 16 + 8]) = res[1];
}

// ---------------------------------------------------------------------------
// Main: 4 independent waves/block, one 64x64 tile per wave, no barriers,
// wave-private LDS. Load phase is INLINE ASM: 16 X dwordx4 + 8 A0 dwordx4
// issued back-to-back, vmcnt(8) (X arrived, A0 in flight under mask VALU),
// vmcnt(0)+sched_barrier before MFMA. Register allocator MUST keep all 24
// result quads live -> 24 outstanding VMEM per wave, guaranteed.
// ---------------------------------------------------------------------------
__global__ __launch_bounds__(256, 3) void psw_main(
    const float* __restrict__ X,
    const ushort* __restrict__ Af,
    float* __restrict__ out)
{
    __shared__ ushort T1t[4][1024];  // per-wave strip^T [kk 16][i 64] bf16 swz

    const int t    = threadIdx.x;
    const int lane = t & 63;
    const int w    = t >> 6;
    const int m  = lane & 15;
    const int lq = lane >> 4;
    const int bj = blockIdx.y;
    const int bk = blockIdx.x * 4 + w;

    const float*  Xb  = X  + (size_t)bj * 64 * D;          // SGPR base
    const ushort* A0b = Af + (size_t)(64 + bj) * 4096;     // SGPR base

    // per-lane byte voffsets: row = it*16+m, col = bk*64 + lq*8 (+mk*32, +h*4)
    const unsigned v0  = (unsigned)(m * (D * 4) + bk * 256 + lq * 32);
    const unsigned v1  = v0 + 1u * 16 * D * 4;
    const unsigned v2  = v0 + 2u * 16 * D * 4;
    const unsigned v3  = v0 + 3u * 16 * D * 4;
    const unsigned va0 = (unsigned)(lane * 16);
    const unsigned va1 = va0 + 4096u;

    f32x4 x0,x1,x2,x3,x4,x5,x6,x7,x8,x9,x10,x11,x12,x13,x14,x15;
    f32x4 a0,a1,a2,a3,a4,a5,a6,a7;

    asm volatile(
        "global_load_dwordx4 %[x0],  %[v0], %[xb]\n\t"
        "global_load_dwordx4 %[x1],  %[v0], %[xb] offset:16\n\t"
        "global_load_dwordx4 %[x2],  %[v0], %[xb] offset:128\n\t"
        "global_load_dwordx4 %[x3],  %[v0], %[xb] offset:144\n\t"
        "global_load_dwordx4 %[x4],  %[v1], %[xb]\n\t"
        "global_load_dwordx4 %[x5],  %[v1], %[xb] offset:16\n\t"
        "global_load_dwordx4 %[x6],  %[v1], %[xb] offset:128\n\t"
        "global_load_dwordx4 %[x7],  %[v1], %[xb] offset:144\n\t"
        "global_load_dwordx4 %[x8],  %[v2], %[xb]\n\t"
        "global_load_dwordx4 %[x9],  %[v2], %[xb] offset:16\n\t"
        "global_load_dwordx4 %[x10], %[v2], %[xb] offset:128\n\t"
        "global_load_dwordx4 %[x11], %[v2], %[xb] offset:144\n\t"
        "global_load_dwordx4 %[x12], %[v3], %[xb]\n\t"
        "global_load_dwordx4 %[x13], %[v3], %[xb] offset:16\n\t"
        "global_load_dwordx4 %[x14], %[v3], %[xb] offset:128\n\t"
        "global_load_dwordx4 %[x15], %[v3], %[xb] offset:144\n\t"
        "global_load_dwordx4 %[a0],  %[va0], %[ab]\n\t"
        "global_load_dwordx4 %[a1],  %[va0], %[ab] offset:1024\n\t"
        "global_load_dwordx4 %[a2],  %[va0], %[ab] offset:2048\n\t"
        "global_load_dwordx4 %[a3],  %[va0], %[ab] offset:3072\n\t"
        "global_load_dwordx4 %[a4],  %[va1], %[ab]\n\t"
        "global_load_dwordx4 %[a5],  %[va1], %[ab] offset:1024\n\t"
        "global_load_dwordx4 %[a6],  %[va1], %[ab] offset:2048\n\t"
        "global_load_dwordx4 %[a7],  %[va1], %[ab] offset:3072\n\t"
        "s_waitcnt vmcnt(8)"
        : [x0]"=&v"(x0), [x1]"=&v"(x1), [x2]"=&v"(x2), [x3]"=&v"(x3),
          [x4]"=&v"(x4), [x5]"=&v"(x5), [x6]"=&v"(x6), [x7]"=&v"(x7),
          [x8]"=&v"(x8), [x9]"=&v"(x9), [x10]"=&v"(x10), [x11]"=&v"(x11),
          [x12]"=&v"(x12), [x13]"=&v"(x13), [x14]"=&v"(x14), [x15]"=&v"(x15),
          [a0]"=&v"(a0), [a1]"=&v"(a1), [a2]"=&v"(a2), [a3]"=&v"(a3),
          [a4]"=&v"(a4), [a5]"=&v"(a5), [a6]"=&v"(a6), [a7]"=&v"(a7)
        : [v0]"v"(v0), [v1]"v"(v1), [v2]"v"(v2), [v3]"v"(v3),
          [va0]"v"(va0), [va1]"v"(va1), [xb]"s"(Xb), [ab]"s"(A0b)
        : "memory");

    // ---- mask top-2-of-4 (lane-local aligned groups), cvt to bf16 ----------
    auto mk8 = [](const f32x4 g0, const f32x4 g1) -> bf16x8 {
        bf16x8 r;
        #pragma unroll
        for (int h = 0; h < 2; ++h) {
            const f32x4 g = h ? g1 : g0;
            const float q0 = fabsf(g[0]), q1 = fabsf(g[1]),
                        q2 = fabsf(g[2]), q3 = fabsf(g[3]);
            const int b01 = q1 >= q0, b02 = q2 >= q0, b03 = q3 >= q0;
            const int b12 = q2 >= q1, b13 = q3 >= q1, b23 = q3 >= q2;
            const int c0n = b01 + b02 + b03;
            const int c1n = (1 - b01) + b12 + b13;
            const int c2n = (2 - b02 - b12) + b23;
            const int c3n = 3 - b03 - b13 - b23;
            r[h * 4 + 0] = (short)f2bf(c0n < 2 ? g[0] : 0.f);
            r[h * 4 + 1] = (short)f2bf(c1n < 2 ? g[1] : 0.f);
            r[h * 4 + 2] = (short)f2bf(c2n < 2 ? g[2] : 0.f);
            r[h * 4 + 3] = (short)f2bf(c3n < 2 ? g[3] : 0.f);
        }
        return r;
    };
    bf16x8 wfr[8];
    wfr[0] = mk8(x0,  x1);  wfr[1] = mk8(x2,  x3);
    wfr[2] = mk8(x4,  x5);  wfr[3] = mk8(x6,  x7);
    wfr[4] = mk8(x8,  x9);  wfr[5] = mk8(x10, x11);
    wfr[6] = mk8(x12, x13); wfr[7] = mk8(x14, x15);

    // drain A0 loads; fence so no MFMA/consumer is hoisted above (rule 18)
    asm volatile("s_waitcnt vmcnt(0)" ::: "memory");
    __builtin_amdgcn_sched_barrier(0);

    bf16x8 a0fr[8] = {
        __builtin_bit_cast(bf16x8, a0), __builtin_bit_cast(bf16x8, a1),
        __builtin_bit_cast(bf16x8, a2), __builtin_bit_cast(bf16x8, a3),
        __builtin_bit_cast(bf16x8, a4), __builtin_bit_cast(bf16x8, a5),
        __builtin_bit_cast(bf16x8, a6), __builtin_bit_cast(bf16x8, a7)};

    // ---- per 16-col output strip: mm1 -> LDS transpose -> mm2 -> store -----
    #pragma unroll
    for (int nt = 0; nt < 4; ++nt) {
        bf16x8 a1fr[2];
        #pragma unroll
        for (int mk = 0; mk < 2; ++mk)
            a1fr[mk] = *reinterpret_cast<const bf16x8*>(
                &Af[(size_t)bk * 4096 + ((nt * 2 + mk) * 64 + lane) * 8]);

        // mm1: T1[:, nt*16+0..15] = mask(X) x A1strip
        f32x4 acc1[4];
        #pragma unroll
        for (int it = 0; it < 4; ++it) acc1[it] = (f32x4){0.f, 0.f, 0.f, 0.f};
        #pragma unroll
        for (int mk = 0; mk < 2; ++mk)
            #pragma unroll
            for (int it = 0; it < 4; ++it)
                acc1[it] = __builtin_amdgcn_mfma_f32_16x16x32_bf16(
                    wfr[it * 2 + mk], a1fr[mk], acc1[it], 0, 0, 0);

        // T1 strip^T to wave-private LDS (in-order within wave, no barrier)
        #pragma unroll
        for (int it = 0; it < 4; ++it) {
            ushort4 tv;
            tv.x = f2bf(acc1[it][0]); tv.y = f2bf(acc1[it][1]);
            tv.z = f2bf(acc1[it][2]); tv.w = f2bf(acc1[it][3]);
            *reinterpret_cast<ushort4*>(
                reinterpret_cast<char*>(T1t[w]) + m * 128
                + ((it * 32 + lq * 8) ^ ((m & 7) << 4))) = tv;
        }

        // mm2: out^T[kk strip][j] = T1strip^T (A) x A0 (B)
        f32x4 accD[4];
        #pragma unroll
        for (int jt = 0; jt < 4; ++jt) accD[jt] = (f32x4){0.f, 0.f, 0.f, 0.f};
        #pragma unroll
        for (int ik = 0; ik < 2; ++ik) {
            const bf16x8 t1fr = *reinterpret_cast<const bf16x8*>(
                reinterpret_cast<char*>(T1t[w]) + m * 128
                + ((ik * 64 + lq * 16) ^ ((m & 7) << 4)));
            #pragma unroll
            for (int jt = 0; jt < 4; ++jt)
                accD[jt] = __builtin_amdgcn_mfma_f32_16x16x32_bf16(
                    t1fr, a0fr[jt * 2 + ik], accD[jt], 0, 0, 0);
        }

        // stores: lane holds out[j=jt*16+m][kk = nt*16 + lq*4 .. +3]
        #pragma unroll
        for (int jt = 0; jt < 4; ++jt)
            *reinterpret_cast<f32x4*>(
                &out[(size_t)(bj * 64 + jt * 16 + m) * D
                     + bk * 64 + nt * 16 + lq * 4]) = accD[jt];
    }
}

extern "C" void kernel_launch(void* const* d_in, const int* in_sizes, int n_in,
                              void* d_out, int out_size, void* d_ws, size_t ws_size,
                              hipStream_t stream) {
    const float* X     = (const float*)d_in[0];
    const float* c0    = (const float*)d_in[1];
    const float* c1    = (const float*)d_in[2];
    // d_in[3] = mask (bool) -- recomputed in-kernel from X, not read
    const int*   perm0 = (const int*)d_in[4];
    const int*   perm1 = (const int*)d_in[5];
    float* out = (float*)d_out;
    ushort* Af = (ushort*)d_ws;    // 128 * 4096 ushorts = 1 MiB

    psw_pre<<<dim3(128), 256, 0, stream>>>(c0, c1, perm0, perm1, Af);
    psw_main<<<dim3(16, 64), 256, 0, stream>>>(X, Af, out);
}